// Round 15
// baseline (154.908 us; speedup 1.0000x reference)
//
#include <hip/hip_runtime.h>
#include <math.h>

#define C_ 512
#define HW_ 16384
#define K_ 19
#define M_ 5
#define P_ 95
#define P2 96
#define NT_ 4096
#define HL2PI 470.49652900081467f  // 0.5 * 512 * ln(2*pi)

typedef __attribute__((ext_vector_type(8))) short short8;
typedef __attribute__((ext_vector_type(4))) int int4v;
typedef __attribute__((ext_vector_type(4))) float float4v;

// fp32 -> bf16 RNE (prep kernel only; main uses packed cvt)
static __device__ __forceinline__ short f2bf(float f) {
  unsigned u = __builtin_bit_cast(unsigned, f);
  unsigned r = (u + 0x7fffu + ((u >> 16) & 1u)) >> 16;
  return (short)r;
}
// pack 2 floats -> bf16x2 via v_cvt_pk_bf16_f32 (no builtin on gfx950)
static __device__ __forceinline__ int pk2(float a, float b) {
  int r;
  asm("v_cvt_pk_bf16_f32 %0, %1, %2" : "=v"(r) : "v"(a), "v"(b));
  return r;
}
// square a bf16x8 fragment in-register
static __device__ __forceinline__ short8 sq8(short8 a) {
  int4v ai = __builtin_bit_cast(int4v, a);
  int4v ri;
#pragma unroll
  for (int j = 0; j < 4; j++) {
    unsigned u = (unsigned)ai[j];
    float lo = __builtin_bit_cast(float, u << 16);
    float hi = __builtin_bit_cast(float, u & 0xffff0000u);
    ri[j] = pk2(lo * lo, hi * hi);
  }
  return __builtin_bit_cast(short8, ri);
}

__device__ __forceinline__ float block_reduce_sum(float v, volatile float* red) {
#pragma unroll
  for (int o = 32; o; o >>= 1) v += __shfl_down(v, o);
  const int lane = threadIdx.x & 63, wv = threadIdx.x >> 6;
  if (lane == 0) red[wv] = v;
  __syncthreads();
  float r = red[0] + red[1] + red[2] + red[3];
  __syncthreads();
  return r;
}

// One block per prototype p. wbf[p][k] bf16 row-major [96][1024]:
//   k <  512: inv_var[c];  k >= 512: mu[c]*inv_var[c]
// cterm[p] = -0.5*q3 - logdet - HL2PI  (fp32)
__global__ __launch_bounds__(256) void prep_kernel(
    const float* __restrict__ means, const float* __restrict__ diag,
    short* __restrict__ wbf, float* __restrict__ cterm) {
  const int p = blockIdx.x;
  const int tid = threadIdx.x;
  __shared__ float red[4];
  if (p >= P_) {  // zero row 95: contributes 0; p=95 never read by max groups
    for (int c = tid; c < C_; c += 256) {
      wbf[p * 1024 + c] = 0;
      wbf[p * 1024 + 512 + c] = 0;
    }
    if (tid == 0) cterm[p] = 0.f;
    return;
  }
  const float* mrow = means + (size_t)p * C_;
  const float* srow = diag + (size_t)p * C_;
  float m0 = mrow[tid], m1 = mrow[tid + 256];
  float ss = block_reduce_sum(m0 * m0 + m1 * m1, red);
  float rden = 1.f / fmaxf(sqrtf(ss), 1e-12f);  // l2_normalize(means)
  float q3 = 0.f, ld = 0.f;
#pragma unroll
  for (int t = 0; t < 2; t++) {
    int c = tid + t * 256;
    float m = mrow[c], s = srow[c];
    float mu = m * rden;
    float iv = 1.f / (s * s);
    wbf[p * 1024 + c] = f2bf(iv);
    wbf[p * 1024 + 512 + c] = f2bf(mu * iv);
    q3 += mu * mu * iv;
    ld += logf(s);
  }
  q3 = block_reduce_sum(q3, red);
  ld = block_reduce_sum(ld, red);
  if (tid == 0) cterm[p] = -0.5f * q3 - ld - HL2PI;
}

// 1 wave = 1 autonomous 16-px tile. ZERO __syncthreads.
// Lane l: px = l&15, owns channels c = 32t + (l>>4)*8 + j (t=0..15, j=0..7)
//  -> chunk t IS the MFMA B-frag for k-slice ks=t (fragment-native registers).
// Pipeline per wave: stage params->LDS -> load x (coalesced 64B segs) + stats
// partials + pack bf16 -> shfl stats (px-group lanes {px,+16,+32,+48}) ->
// in-register RMW x->v -> shfl Sum v^2 -> 16x(sq8 + 12 A-loads(L2) + 12 MFMA)
// -> logp -> wave-private lp (LDS) -> in-wave max/LN-K via ds+shfl -> store.
__global__ __launch_bounds__(64, 3) void main_kernel(
    const float* __restrict__ x,
    const float* __restrict__ fg, const float* __restrict__ fb,
    const float* __restrict__ mg, const float* __restrict__ mb,
    const short* __restrict__ wbf, const float* __restrict__ cterm,
    float* __restrict__ out) {
  __shared__ float fgs[C_], fbs[C_], cts[P2], mgs[20], mbs[20];
  __shared__ float lp[16 * 100];

  const int lane = threadIdx.x;  // 0..63 (single wave)
  const int pxl = lane & 15, q_ = lane >> 4;

  // stage params (same wave -> ds ordering, no barrier needed)
  for (int i = lane; i < C_; i += 64) {
    fgs[i] = fg[i];
    fbs[i] = fb[i];
  }
  for (int i = lane; i < P2; i += 64) cts[i] = cterm[i];
  if (lane < K_) {
    mgs[lane] = mg[lane];
    mbs[lane] = mb[lane];
  }

  const int n0 = blockIdx.x * 16;
  const int b = n0 >> 14;
  const int rem = n0 & 16383;
  const int h = rem >> 7;
  const int w0 = rem & 127;
  const float* xb = x + (size_t)b * C_ * HW_ + h * 128 + w0 + pxl;
  const int cq = q_ * 8;

  // ---- load x + stats partials + pack bf16 into frag-native registers ----
  int pxv[64];
  float s = 0.f, sq = 0.f;
#pragma unroll
  for (int t = 0; t < 16; t++) {
    float xv[8];
#pragma unroll
    for (int j = 0; j < 8; j++) xv[j] = xb[(size_t)(t * 32 + cq + j) * HW_];
#pragma unroll
    for (int j = 0; j < 8; j++) {
      s += xv[j];
      sq = fmaf(xv[j], xv[j], sq);
    }
#pragma unroll
    for (int d = 0; d < 4; d++) pxv[t * 4 + d] = pk2(xv[2 * d], xv[2 * d + 1]);
  }
  s += __shfl_xor(s, 16);
  s += __shfl_xor(s, 32);
  sq += __shfl_xor(sq, 16);
  sq += __shfl_xor(sq, 32);
  const float mean = s * (1.f / C_);
  const float var = sq * (1.f / C_) - mean * mean;
  const float rstd = rsqrtf(var + 1e-5f);

  // ---- in-register RMW: x -> v = (x-mean)*rstd*g + b; Sum v^2 ----
  float s2 = 0.f;
#pragma unroll
  for (int t = 0; t < 16; t++) {
    const int c0 = t * 32 + cq;
    float ga[8], ba[8];
    *(float4v*)(ga) = *(const float4v*)(fgs + c0);
    *(float4v*)(ga + 4) = *(const float4v*)(fgs + c0 + 4);
    *(float4v*)(ba) = *(const float4v*)(fbs + c0);
    *(float4v*)(ba + 4) = *(const float4v*)(fbs + c0 + 4);
#pragma unroll
    for (int d = 0; d < 4; d++) {
      unsigned u = (unsigned)pxv[t * 4 + d];
      float xlo = __builtin_bit_cast(float, u << 16);
      float xhi = __builtin_bit_cast(float, u & 0xffff0000u);
      float vlo = fmaf((xlo - mean) * rstd, ga[2 * d], ba[2 * d]);
      float vhi = fmaf((xhi - mean) * rstd, ga[2 * d + 1], ba[2 * d + 1]);
      s2 = fmaf(vlo, vlo, fmaf(vhi, vhi, s2));
      pxv[t * 4 + d] = pk2(vlo, vhi);
    }
  }
  s2 += __shfl_xor(s2, 16);
  s2 += __shfl_xor(s2, 32);
  const float rn = 1.f / fmaxf(sqrtf(s2), 1e-12f);  // l2_normalize -> epilogue
  const float rn2 = rn * rn;

  // ---- MFMA: B-frags are local registers; A (iv | mu*iv) streamed from L2 ----
  float4v aq1[6] = {}, aq2[6] = {};
  const short* wbase = wbf + ((lane & 15) << 10) + ((lane >> 4) << 3);
#pragma unroll
  for (int ks = 0; ks < 16; ks++) {
    short8 bv = __builtin_bit_cast(short8, *(int4v*)(pxv + ks * 4));
    short8 b2 = sq8(bv);
#pragma unroll
    for (int pt = 0; pt < 6; pt++) {
      const short* wr = wbase + pt * 16384 + ks * 32;
      short8 aiv = *(const short8*)wr;
      short8 amv = *(const short8*)(wr + 512);
      aq1[pt] = __builtin_amdgcn_mfma_f32_16x16x32_bf16(aiv, b2, aq1[pt], 0, 0, 0);
      aq2[pt] = __builtin_amdgcn_mfma_f32_16x16x32_bf16(amv, bv, aq2[pt], 0, 0, 0);
    }
  }

  // ---- logp -> wave-private lp: lane holds (px=lane&15, p=pt*16+q_*4+r) ----
#pragma unroll
  for (int pt = 0; pt < 6; pt++) {
#pragma unroll
    for (int r = 0; r < 4; r++) {
      const int p = pt * 16 + q_ * 4 + r;
      lp[pxl * 100 + p] = fmaf(-0.5f * rn2, aq1[pt][r], fmaf(rn, aq2[pt][r], cts[p]));
    }
  }

  // ---- in-wave max over M + LN over K (two-pass) + store ----
  // lane j: px = j&15, k in {q_ + 4i}; groups {px,+16,+32,+48} cover all 19 k.
  float mk[5];
  float sum = 0.f;
#pragma unroll
  for (int i = 0; i < 5; i++) {
    const int k = q_ + 4 * i;
    if (k < K_) {
      const float* row = lp + pxl * 100 + k * M_;
      float mv = fmaxf(fmaxf(row[0], row[1]), fmaxf(row[2], row[3]));
      mv = fmaxf(mv, row[4]);
      mk[i] = mv;
      sum += mv;
    } else {
      mk[i] = 0.f;
    }
  }
  sum += __shfl_xor(sum, 16);
  sum += __shfl_xor(sum, 32);
  const float m2 = sum * (1.f / K_);
  float qq = 0.f;
#pragma unroll
  for (int i = 0; i < 5; i++) {
    const int k = q_ + 4 * i;
    if (k < K_) {
      float d = mk[i] - m2;
      qq = fmaf(d, d, qq);
    }
  }
  qq += __shfl_xor(qq, 16);
  qq += __shfl_xor(qq, 32);
  const float rstd2 = rsqrtf(qq * (1.f / K_) + 1e-5f);

  float* ob = out + (size_t)(b * K_) * HW_ + h * 128 + w0 + pxl;
#pragma unroll
  for (int i = 0; i < 5; i++) {
    const int k = q_ + 4 * i;
    if (k < K_) ob[(size_t)k * HW_] = fmaf((mk[i] - m2) * rstd2, mgs[k], mbs[k]);
  }
}

extern "C" void kernel_launch(void* const* d_in, const int* in_sizes, int n_in,
                              void* d_out, int out_size, void* d_ws, size_t ws_size,
                              hipStream_t stream) {
  const float* x = (const float*)d_in[0];
  const float* means = (const float*)d_in[1];
  const float* diag = (const float*)d_in[2];
  const float* fg = (const float*)d_in[3];
  const float* fb = (const float*)d_in[4];
  const float* mg = (const float*)d_in[5];
  const float* mb = (const float*)d_in[6];
  float* out = (float*)d_out;

  short* wbf = (short*)d_ws;                                     // 96*1024*2 B
  float* cterm = (float*)((char*)d_ws + (size_t)P2 * 1024 * 2);  // +96*4 B

  prep_kernel<<<P2, 256, 0, stream>>>(means, diag, wbf, cterm);
  main_kernel<<<NT_, 64, 0, stream>>>(x, fg, fb, mg, mb, wbf, cterm, out);
}

// Round 16
// 69.230 us; speedup vs baseline: 2.2376x; 2.2376x over previous
//
#include <hip/hip_runtime.h>
#include <math.h>

#define C_ 512
#define HW_ 16384
#define K_ 19
#define M_ 5
#define P_ 95
#define P2 96
#define TPX 32
#define NBLK 2048
#define HL2PI 470.49652900081467f  // 0.5 * 512 * ln(2*pi)

typedef __attribute__((ext_vector_type(8))) short short8;
typedef __attribute__((ext_vector_type(4))) int int4v;
typedef __attribute__((ext_vector_type(4))) float float4v;

// fp32 -> bf16 RNE (prep kernel only; main uses packed cvt)
static __device__ __forceinline__ short f2bf(float f) {
  unsigned u = __builtin_bit_cast(unsigned, f);
  unsigned r = (u + 0x7fffu + ((u >> 16) & 1u)) >> 16;
  return (short)r;
}
static __device__ __forceinline__ float bf2f(short s) {
  return __builtin_bit_cast(float, ((unsigned)(unsigned short)s) << 16);
}

// pack 2 floats -> bf16x2 via v_cvt_pk_bf16_f32 (no builtin on gfx950)
static __device__ __forceinline__ int pk2(float a, float b) {
  int r;
  asm("v_cvt_pk_bf16_f32 %0, %1, %2" : "=v"(r) : "v"(a), "v"(b));
  return r;
}

// square a bf16x8 fragment in-register: unpack pairs, square, packed-repack
static __device__ __forceinline__ short8 sq8(short8 a) {
  int4v ai = __builtin_bit_cast(int4v, a);
  int4v ri;
#pragma unroll
  for (int j = 0; j < 4; j++) {
    unsigned u = (unsigned)ai[j];
    float lo = __builtin_bit_cast(float, u << 16);
    float hi = __builtin_bit_cast(float, u & 0xffff0000u);
    ri[j] = pk2(lo * lo, hi * hi);
  }
  return __builtin_bit_cast(short8, ri);
}

__device__ __forceinline__ float block_reduce_sum(float v, volatile float* red) {
#pragma unroll
  for (int o = 32; o; o >>= 1) v += __shfl_down(v, o);
  const int lane = threadIdx.x & 63, wv = threadIdx.x >> 6;
  if (lane == 0) red[wv] = v;
  __syncthreads();
  float r = red[0] + red[1] + red[2] + red[3];
  __syncthreads();
  return r;
}

// One block per prototype p. wbf[p][k] bf16 row-major [96][1024]:
//   k <  512: inv_var[c];  k >= 512: mu[c]*inv_var[c]
// cterm[p] = -0.5*q3 - logdet - HL2PI  (fp32)
__global__ __launch_bounds__(256) void prep_kernel(
    const float* __restrict__ means, const float* __restrict__ diag,
    short* __restrict__ wbf, float* __restrict__ cterm) {
  const int p = blockIdx.x;
  const int tid = threadIdx.x;
  __shared__ float red[4];
  if (p >= P_) {  // zero-pad row 95: contributes 0, never selected in max
    for (int c = tid; c < C_; c += 256) {
      wbf[p * 1024 + c] = 0;
      wbf[p * 1024 + 512 + c] = 0;
    }
    if (tid == 0) cterm[p] = 0.f;
    return;
  }
  const float* mrow = means + (size_t)p * C_;
  const float* srow = diag + (size_t)p * C_;
  float m0 = mrow[tid], m1 = mrow[tid + 256];
  float ss = block_reduce_sum(m0 * m0 + m1 * m1, red);
  float rden = 1.f / fmaxf(sqrtf(ss), 1e-12f);  // l2_normalize(means)
  float q3 = 0.f, ld = 0.f;
#pragma unroll
  for (int t = 0; t < 2; t++) {
    int c = tid + t * 256;
    float m = mrow[c], s = srow[c];
    float mu = m * rden;
    float iv = 1.f / (s * s);
    wbf[p * 1024 + c] = f2bf(iv);
    wbf[p * 1024 + 512 + c] = f2bf(mu * iv);
    q3 += mu * mu * iv;
    ld += logf(s);
  }
  q3 = block_reduce_sum(q3, red);
  ld = block_reduce_sum(ld, red);
  if (tid == 0) cterm[p] = -0.5f * q3 - ld - HL2PI;
}

// One block = 32 pixels, 256 threads (4 waves). R12 structure (69.4us verified)
// with single-stage epilogue: khalf0 -> lp1, khalf1 -> lp2 (disjoint, one
// barrier), max-over-M fuses lp1+lp2 (R3/R4-verified pattern).
// Phase A: thread (cg=tid>>3, q=tid&7) loads 16 float4 along W; component
// transpose in-register -> bf16 x frags in LDS. Phase B: in-place LDS RMW.
__global__ __launch_bounds__(256) void main_kernel(
    const float* __restrict__ x,
    const float* __restrict__ fg, const float* __restrict__ fb,
    const float* __restrict__ mg, const float* __restrict__ mb,
    const short* __restrict__ wbf, const float* __restrict__ cterm,
    float* __restrict__ out) {
  __shared__ __align__(16) char raw[32768];  // x/v frags; later lp1 @0, lp2 @16384
  __shared__ float redS[128], redQ[128];     // 32 slots x float4
  __shared__ float meanA[TPX], rstdA[TPX], rnA[TPX], rn2A[TPX];
  __shared__ float mean2A[TPX], rstd2A[TPX];
  __shared__ float mpr[TPX * 20];

  const int tid = threadIdx.x;
  const int wv = tid >> 6, lane = tid & 63;
  const int cg = tid >> 3, q = tid & 7;  // channel group (16c), pixel quad
  const int n0 = blockIdx.x * TPX;
  const int b = n0 >> 14;
  const int rem = n0 & 16383;
  const int h = rem >> 7;
  const int w0 = rem & 127;
  const int c16 = cg * 16;
  const int blkw = (q >> 2) * 16 + (cg >> 1);
  const int sbase = (q & 3) * 2 + (cg & 1);
  const float* xp4 = x + (size_t)b * C_ * HW_ + h * 128 + w0 + q * 4;

  // ---- Phase A: float4 loads, stats accumulate, bf16 x-frags -> LDS ----
  float4v s4 = {0.f, 0.f, 0.f, 0.f}, q4 = {0.f, 0.f, 0.f, 0.f};
#pragma unroll
  for (int hc = 0; hc < 2; hc++) {
    float4v xq[8];
#pragma unroll
    for (int i = 0; i < 8; i++)
      xq[i] = *(const float4v*)(xp4 + (size_t)(c16 + hc * 8 + i) * HW_);
#pragma unroll
    for (int i = 0; i < 8; i++) {
      s4 += xq[i];
      q4 += xq[i] * xq[i];
    }
#pragma unroll
    for (int r = 0; r < 4; r++) {
      int4v pk;
#pragma unroll
      for (int j2 = 0; j2 < 4; j2++) pk[j2] = pk2(xq[2 * j2][r], xq[2 * j2 + 1][r]);
      *(int4v*)(raw + blkw * 1024 + ((hc * 4 + r) * 8 + sbase) * 16) = pk;
    }
  }
  // wave reduce over cg (lanes stride 8), then cross-wave via 1KB LDS
#pragma unroll
  for (int o = 8; o < 64; o <<= 1) {
#pragma unroll
    for (int c = 0; c < 4; c++) {
      s4[c] += __shfl_down(s4[c], o);
      q4[c] += __shfl_down(q4[c], o);
    }
  }
  if (lane < 8) {
    *(float4v*)(redS + (wv * 8 + lane) * 4) = s4;
    *(float4v*)(redQ + (wv * 8 + lane) * 4) = q4;
  }
  __syncthreads();
  if (tid < 32) {  // px = tid: q' = tid>>2, comp = tid&3
    float ss = 0.f, qq = 0.f;
#pragma unroll
    for (int w = 0; w < 4; w++) {
      ss += redS[(w * 8 + (tid >> 2)) * 4 + (tid & 3)];
      qq += redQ[(w * 8 + (tid >> 2)) * 4 + (tid & 3)];
    }
    float mean = ss * (1.f / C_);
    float var = qq * (1.f / C_) - mean * mean;
    meanA[tid] = mean;
    rstdA[tid] = rsqrtf(var + 1e-5f);
  }
  __syncthreads();

  // ---- Phase B: in-place LDS RMW x -> v = LN(x)*g+b; accumulate Sum v^2 ----
  {
    float fga[16], fba[16];
#pragma unroll
    for (int i = 0; i < 4; i++) {
      *(float4v*)(fga + i * 4) = *(const float4v*)(fg + c16 + i * 4);
      *(float4v*)(fba + i * 4) = *(const float4v*)(fb + c16 + i * 4);
    }
    const float4v mean4 = *(const float4v*)(meanA + q * 4);
    const float4v rstd4 = *(const float4v*)(rstdA + q * 4);
    float4v s2 = {0.f, 0.f, 0.f, 0.f};
#pragma unroll
    for (int hc = 0; hc < 2; hc++) {
#pragma unroll
      for (int r = 0; r < 4; r++) {
        char* ad = raw + blkw * 1024 + ((hc * 4 + r) * 8 + sbase) * 16;
        short8 xc = *(short8*)ad;
        const float m = mean4[r], sd = rstd4[r];
        float vv[8];
#pragma unroll
        for (int j = 0; j < 8; j++) {
          float v = fmaf((bf2f(xc[j]) - m) * sd, fga[hc * 8 + j], fba[hc * 8 + j]);
          s2[r] = fmaf(v, v, s2[r]);
          vv[j] = v;
        }
        int4v pk;
#pragma unroll
        for (int j2 = 0; j2 < 4; j2++) pk[j2] = pk2(vv[2 * j2], vv[2 * j2 + 1]);
        *(int4v*)ad = pk;
      }
    }
#pragma unroll
    for (int o = 8; o < 64; o <<= 1) {
#pragma unroll
      for (int c = 0; c < 4; c++) s2[c] += __shfl_down(s2[c], o);
    }
    if (lane < 8) *(float4v*)(redS + (wv * 8 + lane) * 4) = s2;
  }
  __syncthreads();
  if (tid < 32) {
    float ss = 0.f;
#pragma unroll
    for (int w = 0; w < 4; w++) ss += redS[(w * 8 + (tid >> 2)) * 4 + (tid & 3)];
    float rn = 1.f / fmaxf(sqrtf(ss), 1e-12f);  // l2_normalize folded into epilogue
    rnA[tid] = rn;
    rn2A[tid] = rn * rn;
  }
  __syncthreads();

  // ---- MFMA: wave = (khalf = wv>>1, phalf = wv&1), 3 p-tiles x 2 px-tiles ----
  const int pbase = (wv & 1) * 3;
  const int khalf = wv >> 1;
  const int lm = lane & 15, lk = lane >> 4;
  const int slotR =
      ((((lane >> 4) & 1) * 4 + (lane & 3)) * 8 + ((lane >> 2) & 3) * 2 + ((lane >> 5) & 1)) * 16;
  float4v acc[3][2] = {{}, {}, {}};
  const short* wrow = wbf + (((pbase * 16 + lm) << 10) + (khalf << 9) + (lk << 3));
#pragma unroll 4
  for (int ksl = 0; ksl < 16; ksl++) {
    short8 a0 = *(const short8*)(wrow + ksl * 32);
    short8 a1 = *(const short8*)(wrow + 16384 + ksl * 32);
    short8 a2 = *(const short8*)(wrow + 32768 + ksl * 32);
    short8 b0 = *(const short8*)(raw + ksl * 1024 + slotR);
    short8 b1 = *(const short8*)(raw + (16 + ksl) * 1024 + slotR);
    if (khalf == 0) {  // wave-uniform branch
      b0 = sq8(b0);
      b1 = sq8(b1);
    }
    acc[0][0] = __builtin_amdgcn_mfma_f32_16x16x32_bf16(a0, b0, acc[0][0], 0, 0, 0);
    acc[0][1] = __builtin_amdgcn_mfma_f32_16x16x32_bf16(a0, b1, acc[0][1], 0, 0, 0);
    acc[1][0] = __builtin_amdgcn_mfma_f32_16x16x32_bf16(a1, b0, acc[1][0], 0, 0, 0);
    acc[1][1] = __builtin_amdgcn_mfma_f32_16x16x32_bf16(a1, b1, acc[1][1], 0, 0, 0);
    acc[2][0] = __builtin_amdgcn_mfma_f32_16x16x32_bf16(a2, b0, acc[2][0], 0, 0, 0);
    acc[2][1] = __builtin_amdgcn_mfma_f32_16x16x32_bf16(a2, b1, acc[2][1], 0, 0, 0);
  }
  __syncthreads();  // u dead; alias raw as lp1[32][100] @0, lp2[32][100] @16384
  float* lp1 = (float*)raw;
  float* lp2 = (float*)(raw + 16384);

  // single-stage epilogue: both khalf groups write concurrently (disjoint)
  if (khalf == 0) {
#pragma unroll
    for (int i = 0; i < 3; i++) {
      const int prow = (pbase + i) * 16 + lk * 4;
#pragma unroll
      for (int r = 0; r < 4; r++) {
        const float ct = cterm[prow + r];
#pragma unroll
        for (int t2 = 0; t2 < 2; t2++) {
          const int pxx = t2 * 16 + lm;
          lp1[pxx * 100 + prow + r] = fmaf(-0.5f * rn2A[pxx], acc[i][t2][r], ct);
        }
      }
    }
  } else {
#pragma unroll
    for (int i = 0; i < 3; i++) {
      const int prow = (pbase + i) * 16 + lk * 4;
#pragma unroll
      for (int r = 0; r < 4; r++) {
#pragma unroll
        for (int t2 = 0; t2 < 2; t2++) {
          const int pxx = t2 * 16 + lm;
          lp2[pxx * 100 + prow + r] = rnA[pxx] * acc[i][t2][r];
        }
      }
    }
  }
  __syncthreads();

  // ---- max over M (fusing lp1+lp2 add) ----
  for (int idx = tid; idx < TPX * K_; idx += 256) {
    const int pxx = idx / K_;
    const int k = idx - pxx * K_;
    const float* r1 = lp1 + pxx * 100 + k * M_;
    const float* r2 = lp2 + pxx * 100 + k * M_;
    float mv = r1[0] + r2[0];
#pragma unroll
    for (int m = 1; m < M_; m++) mv = fmaxf(mv, r1[m] + r2[m]);
    mpr[pxx * 20 + k] = mv;
  }
  __syncthreads();
  // ---- LN over K (two-pass: values ~ -470, var ~ 1e-3) ----
  if (tid < 32) {
    float ss = 0.f;
    for (int k = 0; k < K_; k++) ss += mpr[tid * 20 + k];
    float m2 = ss * (1.f / K_);
    float qq = 0.f;
    for (int k = 0; k < K_; k++) {
      float d = mpr[tid * 20 + k] - m2;
      qq += d * d;
    }
    mean2A[tid] = m2;
    rstd2A[tid] = rsqrtf(qq * (1.f / K_) + 1e-5f);
  }
  __syncthreads();
  // ---- coalesced store (B,K,H,W) ----
  float* obase = out + ((size_t)(b * K_) * 128 + h) * 128 + w0;
  for (int idx = tid; idx < TPX * K_; idx += 256) {
    const int k = idx >> 5, pxx = idx & 31;
    float v = fmaf((mpr[pxx * 20 + k] - mean2A[pxx]) * rstd2A[pxx], mg[k], mb[k]);
    obase[(size_t)k * HW_ + pxx] = v;
  }
}

extern "C" void kernel_launch(void* const* d_in, const int* in_sizes, int n_in,
                              void* d_out, int out_size, void* d_ws, size_t ws_size,
                              hipStream_t stream) {
  const float* x = (const float*)d_in[0];
  const float* means = (const float*)d_in[1];
  const float* diag = (const float*)d_in[2];
  const float* fg = (const float*)d_in[3];
  const float* fb = (const float*)d_in[4];
  const float* mg = (const float*)d_in[5];
  const float* mb = (const float*)d_in[6];
  float* out = (float*)d_out;

  short* wbf = (short*)d_ws;                                     // 96*1024*2 B
  float* cterm = (float*)((char*)d_ws + (size_t)P2 * 1024 * 2);  // +96*4 B

  prep_kernel<<<P2, 256, 0, stream>>>(means, diag, wbf, cterm);
  main_kernel<<<NBLK, 256, 0, stream>>>(x, fg, fb, mg, mb, wbf, cterm, out);
}